// Round 4
// baseline (261.501 us; speedup 1.0000x reference)
//
#include <hip/hip_runtime.h>

// Fully-fused conv3x3(pad1)->pool2x2->conv3x3(pad1)->pool2x2, fp32.
// x: [2,1,4096,4096], W1/W2: [1,1,3,3], out: [2,1,1024,1024].
//
// Round-4: wave-autonomous streaming, ZERO LDS, ZERO barriers.
//  - lane owns 4 x-cols (1 float4/row) -> 2 h2-cols -> 1 out-col
//  - conv1 partial row sums rotate in registers (accA/accB); pool1 pairs ->
//    h2 row (2 floats/lane); conv2 rotation consumes it immediately, with
//    shfl_up/down providing the +-1 h2 col taps; pool2 pairs -> out row
//  - wave-boundary h2 halo col: lanes 0/63 redundantly compute it from one
//    extra clamped float4/row (which also provides the x edge neighbors)
//  - DOUT=4 out rows/wave -> 8192 waves -> 32 waves/CU (launch_bounds(256,8))
//  - bijective XCD swizzle: each XCD gets 256 consecutive band-major blocks
//    so the 6-row band overlap is served by that XCD's L2

#define HIMG 4096
#define ODIM 1024
#define H2W  2048

__global__ __launch_bounds__(256, 8)
void fused_net_v4(const float* __restrict__ x, const float* __restrict__ W1,
                  const float* __restrict__ W2, float* __restrict__ out)
{
    // ---- block remap: 2048 blocks, 8 XCDs, band-major within XCD ----
    const int id  = blockIdx.x;
    const int nid = (id & 7) * 256 + (id >> 3);
    const int img    = nid >> 10;
    const int rr     = nid & 1023;
    const int band   = rr >> 2;        // 256 bands of 4 output rows
    const int colseg = rr & 3;         // 4 col segments x 256 out cols

    const int tid  = threadIdx.x;
    const int lane = tid & 63;
    const int oc   = (colseg << 8) + tid;   // out col
    const int o0   = band << 2;             // first out row
    const int x0   = oc << 2;               // first own x col
    const long xoff = (long)img * HIMG * HIMG;

    float w1[9], w2[9];
#pragma unroll
    for (int i = 0; i < 9; ++i) { w1[i] = W1[i]; w2[i] = W2[i]; }

    const bool haloL = (lane == 0);
    const bool haloR = (lane == 63);
    const bool halo  = haloL | haloR;
    const bool hvalid = haloL ? (oc > 0) : (oc < ODIM - 1);  // halo h2 col inside image
    int hx = haloL ? x0 - 4 : x0 + 4;
    if (hx < 0) hx = 0;
    if (hx > HIMG - 4) hx = HIMG - 4;

    const int xr0 = (o0 << 2) - 3;   // first x row streamed (22 rows total)

    float accA[4] = {0,0,0,0}, accB[4] = {0,0,0,0};   // conv1 rotation
    float accAh[2] = {0,0}, accBh[2] = {0,0};         // halo conv1 rotation
    float dA[2] = {0,0}, dB[2] = {0,0};               // conv2 rotation
    float p0 = 0.f, p1 = 0.f;                         // stashed h3 row 2a

    auto rowA = [&](int t, float (&dd)[4], float (&ddh)[2]) {
        const int gy = xr0 + t;
        float4 v  = make_float4(0.f, 0.f, 0.f, 0.f);
        float4 vh = make_float4(0.f, 0.f, 0.f, 0.f);
        if ((unsigned)gy < (unsigned)HIMG) {           // wave-uniform
            const float* xrow = x + xoff + (long)gy * HIMG;
            v = *(const float4*)(xrow + x0);
            if (halo) vh = *(const float4*)(xrow + hx);
        }
        float xl = __shfl_up(v.w, 1);
        float xr = __shfl_down(v.x, 1);
        if (haloL) xl = hvalid ? vh.w : 0.f;           // x[x0-1]
        if (haloR) xr = hvalid ? vh.x : 0.f;           // x[x0+4]
        const float xv[6] = {xl, v.x, v.y, v.z, v.w, xr};
#pragma unroll
        for (int j = 0; j < 4; ++j) {
            float d = accA[j];
            d = fmaf(w1[6], xv[j], d); d = fmaf(w1[7], xv[j+1], d); d = fmaf(w1[8], xv[j+2], d);
            float a = accB[j];
            a = fmaf(w1[3], xv[j], a); a = fmaf(w1[4], xv[j+1], a); a = fmaf(w1[5], xv[j+2], a);
            float b = w1[0] * xv[j];
            b = fmaf(w1[1], xv[j+1], b); b = fmaf(w1[2], xv[j+2], b);
            dd[j] = d; accA[j] = a; accB[j] = b;
        }
        if (halo) {   // halo conv1 cols: lane0 -> {x0-2,x0-1}, lane63 -> {x0+4,x0+5}
            const float t0 = haloL ? vh.y : v.w;
            const float t1 = haloL ? vh.z : vh.x;
            const float t2 = haloL ? vh.w : vh.y;
            const float t3 = haloL ? v.x  : vh.z;
            const float hv4[4] = {t0, t1, t2, t3};
#pragma unroll
            for (int j = 0; j < 2; ++j) {
                float d = accAh[j];
                d = fmaf(w1[6], hv4[j], d); d = fmaf(w1[7], hv4[j+1], d); d = fmaf(w1[8], hv4[j+2], d);
                float a = accBh[j];
                a = fmaf(w1[3], hv4[j], a); a = fmaf(w1[4], hv4[j+1], a); a = fmaf(w1[5], hv4[j+2], a);
                float b = w1[0] * hv4[j];
                b = fmaf(w1[1], hv4[j+1], b); b = fmaf(w1[2], hv4[j+2], b);
                ddh[j] = d; accAh[j] = a; accBh[j] = b;
            }
        }
    };

    float dd0[4], dd1[4], ddh0[2], ddh1[2];
    rowA(0, dd0, ddh0);          // prime conv1 rotation (results discarded)
    rowA(1, dd0, ddh0);

    const long obase = (long)img * ODIM * ODIM + oc;

#pragma unroll 2
    for (int s = 0; s < 10; ++s) {     // 10 h2 rows: P = 2*o0-1+s
        rowA(2 * s + 2, dd0, ddh0);    // conv rows 2P, 2P+1
        rowA(2 * s + 3, dd1, ddh1);

        float hvx = fmaxf(fmaxf(dd0[0], dd0[1]), fmaxf(dd1[0], dd1[1]));
        float hvy = fmaxf(fmaxf(dd0[2], dd0[3]), fmaxf(dd1[2], dd1[3]));
        float hh  = fmaxf(fmaxf(ddh0[0], ddh0[1]), fmaxf(ddh1[0], ddh1[1]));
        const int P = 2 * o0 - 1 + s;
        const bool pok = (unsigned)P < (unsigned)H2W;   // conv2 zero-pad rows
        if (!pok) { hvx = 0.f; hvy = 0.f; }
        if (!pok || !hvalid) hh = 0.f;                  // conv2 zero-pad cols

        const float su = __shfl_up(hvy, 1);
        const float sd = __shfl_down(hvx, 1);
        const float s1 = haloL ? hh : su;   // h2[P][2oc-1]
        const float s4 = haloR ? hh : sd;   // h2[P][2oc+2]

        // conv2 rotation over h2 rows; 2 h3 cols per lane
        float e0 = dA[0];
        e0 = fmaf(w2[6], s1, e0); e0 = fmaf(w2[7], hvx, e0); e0 = fmaf(w2[8], hvy, e0);
        float a0 = dB[0];
        a0 = fmaf(w2[3], s1, a0); a0 = fmaf(w2[4], hvx, a0); a0 = fmaf(w2[5], hvy, a0);
        float b0 = w2[0] * s1;  b0 = fmaf(w2[1], hvx, b0); b0 = fmaf(w2[2], hvy, b0);
        float e1 = dA[1];
        e1 = fmaf(w2[6], hvx, e1); e1 = fmaf(w2[7], hvy, e1); e1 = fmaf(w2[8], s4, e1);
        float a1 = dB[1];
        a1 = fmaf(w2[3], hvx, a1); a1 = fmaf(w2[4], hvy, a1); a1 = fmaf(w2[5], s4, a1);
        float b1 = w2[0] * hvx; b1 = fmaf(w2[1], hvy, b1); b1 = fmaf(w2[2], s4, b1);
        dA[0] = a0; dB[0] = b0; dA[1] = a1; dB[1] = b1;

        if (s >= 2) {
            if (s & 1) {   // completed h3 row 2a+1 -> pool2 -> out row a
                const float res = fmaxf(fmaxf(p0, p1), fmaxf(e0, e1));
                out[obase + (long)(o0 + ((s - 3) >> 1)) * ODIM] = res;
            } else {       // completed h3 row 2a -> stash
                p0 = e0; p1 = e1;
            }
        }
    }
}

extern "C" void kernel_launch(void* const* d_in, const int* in_sizes, int n_in,
                              void* d_out, int out_size, void* d_ws, size_t ws_size,
                              hipStream_t stream) {
    const float* x  = (const float*)d_in[0];
    const float* W1 = (const float*)d_in[1];
    const float* W2 = (const float*)d_in[2];
    float* out = (float*)d_out;

    fused_net_v4<<<dim3(2048), dim3(256), 0, stream>>>(x, W1, W2, out);
}

// Round 5
// 211.766 us; speedup vs baseline: 1.2349x; 1.2349x over previous
//
#include <hip/hip_runtime.h>

// Fully-fused conv3x3(pad1)->pool2x2->conv3x3(pad1)->pool2x2, fp32.
// x: [2,1,4096,4096], W1/W2: [1,1,3,3], out: [2,1,1024,1024].
//
// Round-5: wave-autonomous streaming, zero LDS, zero barriers, plus:
//  - 4-deep explicit load pipeline (float4 circular buffer, fully unrolled,
//    static indices) -> 4 loads in flight per wave instead of 1 (r4's stall)
//  - wave-overlap halo: waves overlap by 2 out cols; lanes 0/63 are
//    sacrificial producers (their h2 feeds neighbors via shfl, own output
//    masked) -> no extra halo loads, no divergent halo FMA block
//  - DOUT=8 out rows/wave: fetch amplification 38/32 = 1.19 (was 1.375)
//  - 17 waves cover 1024 out cols; 4352 waves total; ~17 waves/CU

#define HIMG 4096
#define ODIM 1024
#define H2W  2048
#define NBAND 128            // bands per image (8 out rows each)
#define WSEG 17              // waves per band (62 unique out cols each)
#define WPI  (NBAND * WSEG)  // 2176 waves per image
#define NROWS 38             // x rows streamed per band

__global__ __launch_bounds__(256, 8)
void fused_v5(const float* __restrict__ x, const float* __restrict__ W1,
              const float* __restrict__ W2, float* __restrict__ out)
{
    const int lane = threadIdx.x & 63;
    const int gwid = blockIdx.x * 4 + (threadIdx.x >> 6);
    const int img  = (gwid >= WPI) ? 1 : 0;
    const int r    = gwid - img * WPI;
    const int band = r / WSEG;
    const int wseg = r - band * WSEG;

    float w1[9], w2[9];
#pragma unroll
    for (int i = 0; i < 9; ++i) { w1[i] = W1[i]; w2[i] = W2[i]; }

    // lane geometry: out col oc; lanes 0 and 63 are sacrificial halo producers
    const int oc = 62 * wseg - 1 + lane;
    const int o0 = band * 8;
    int x0 = oc * 4;
    x0 = x0 < 0 ? 0 : (x0 > HIMG - 4 ? HIMG - 4 : x0);
    const bool lE   = (x0 == 0);            // image left edge: xl = 0
    const bool rE   = (x0 == HIMG - 4);     // image right edge: xr = 0
    const bool zs1  = (oc == 0);            // h2 col -1 is zero padding
    const bool zs4  = (oc == ODIM - 1);     // h2 col 2048 is zero padding
    const bool doSt = (lane >= 1) & (lane <= 62) & ((unsigned)oc < (unsigned)ODIM);

    const int xr0 = 32 * band - 3;          // first x row of band
    const float* xb = x + (long)img * HIMG * HIMG + x0;

    auto LD = [&](int t) -> float4 {
        int gy  = xr0 + t;
        int gyc = gy < 0 ? 0 : (gy > HIMG - 1 ? HIMG - 1 : gy);   // clamped addr
        float4 v = *(const float4*)(xb + (long)gyc * HIMG);
        if (gy != gyc) { v.x = 0.f; v.y = 0.f; v.z = 0.f; v.w = 0.f; }  // uniform
        return v;
    };

    float4 buf[4];
    buf[0] = LD(0); buf[1] = LD(1); buf[2] = LD(2); buf[3] = LD(3);

    float accA[4] = {0,0,0,0}, accB[4] = {0,0,0,0};   // conv1 row rotation
    float dd0[4], dd1[4];
    float dA0 = 0, dA1 = 0, dB0 = 0, dB1 = 0, p0 = 0, p1 = 0;  // conv2/pool2

    auto ROW = [&](int t, float (&dd)[4]) {
        float4 v = buf[t & 3];
        if (t + 4 < NROWS) buf[t & 3] = LD(t + 4);    // keep 4 in flight
        float xl = __shfl_up(v.w, 1);
        float xr = __shfl_down(v.x, 1);
        if (lE) xl = 0.f;
        if (rE) xr = 0.f;
        const float xv[6] = {xl, v.x, v.y, v.z, v.w, xr};
#pragma unroll
        for (int j = 0; j < 4; ++j) {
            float d = accA[j];                         // completes conv row gy-1
            d = fmaf(w1[6], xv[j], d); d = fmaf(w1[7], xv[j+1], d); d = fmaf(w1[8], xv[j+2], d);
            float a = accB[j];                         // conv row gy
            a = fmaf(w1[3], xv[j], a); a = fmaf(w1[4], xv[j+1], a); a = fmaf(w1[5], xv[j+2], a);
            float b = w1[0] * xv[j];                   // conv row gy+1
            b = fmaf(w1[1], xv[j+1], b); b = fmaf(w1[2], xv[j+2], b);
            dd[j] = d; accA[j] = a; accB[j] = b;
        }
    };

    ROW(0, dd0); ROW(1, dd0);                          // prime (discard)
    const long ob = (long)img * ODIM * ODIM + (long)o0 * ODIM + oc;

#pragma unroll
    for (int s = 0; s < 18; ++s) {                     // 18 h2 rows: P = 2*o0-1+s
        ROW(2 * s + 2, dd0);
        ROW(2 * s + 3, dd1);
        float hvx = fmaxf(fmaxf(dd0[0], dd0[1]), fmaxf(dd1[0], dd1[1]));
        float hvy = fmaxf(fmaxf(dd0[2], dd0[3]), fmaxf(dd1[2], dd1[3]));
        const int P = 2 * o0 - 1 + s;
        if ((unsigned)P >= (unsigned)H2W) { hvx = 0.f; hvy = 0.f; }  // conv2 row pad
        float su = __shfl_up(hvy, 1);                  // h2[P][2oc-1] from lane-1
        float sd = __shfl_down(hvx, 1);                // h2[P][2oc+2] from lane+1
        const float s1 = zs1 ? 0.f : su;
        const float s4 = zs4 ? 0.f : sd;
        // conv2 rotation: h2 row P feeds h3 rows P+1/P/P-1 (w2 rows 0/1/2)
        float e0 = dA0;
        e0 = fmaf(w2[6], s1, e0); e0 = fmaf(w2[7], hvx, e0); e0 = fmaf(w2[8], hvy, e0);
        float a0 = dB0;
        a0 = fmaf(w2[3], s1, a0); a0 = fmaf(w2[4], hvx, a0); a0 = fmaf(w2[5], hvy, a0);
        float b0 = w2[0] * s1;  b0 = fmaf(w2[1], hvx, b0); b0 = fmaf(w2[2], hvy, b0);
        float e1 = dA1;
        e1 = fmaf(w2[6], hvx, e1); e1 = fmaf(w2[7], hvy, e1); e1 = fmaf(w2[8], s4, e1);
        float a1 = dB1;
        a1 = fmaf(w2[3], hvx, a1); a1 = fmaf(w2[4], hvy, a1); a1 = fmaf(w2[5], s4, a1);
        float b1 = w2[0] * hvx; b1 = fmaf(w2[1], hvy, b1); b1 = fmaf(w2[2], s4, b1);
        dA0 = a0; dB0 = b0; dA1 = a1; dB1 = b1;
        if (s >= 2) {
            if (s & 1) {                               // completed h3 row 2a+1
                const float res = fmaxf(fmaxf(p0, p1), fmaxf(e0, e1));
                if (doSt) out[ob + (long)((s - 3) >> 1) * ODIM] = res;
            } else {                                   // completed h3 row 2a
                p0 = e0; p1 = e1;
            }
        }
    }
}

extern "C" void kernel_launch(void* const* d_in, const int* in_sizes, int n_in,
                              void* d_out, int out_size, void* d_ws, size_t ws_size,
                              hipStream_t stream) {
    const float* x  = (const float*)d_in[0];
    const float* W1 = (const float*)d_in[1];
    const float* W2 = (const float*)d_in[2];
    float* out = (float*)d_out;

    // 2 images * 2176 waves = 4352 waves = 1088 blocks of 4 waves
    fused_v5<<<dim3(1088), dim3(256), 0, stream>>>(x, W1, W2, out);
}

// Round 6
// 209.109 us; speedup vs baseline: 1.2505x; 1.0127x over previous
//
#include <hip/hip_runtime.h>

// Fully-fused conv3x3(pad1)->pool2x2->conv3x3(pad1)->pool2x2, fp32.
// x: [2,1,4096,4096], W1/W2: [1,1,3,3], out: [2,1,1024,1024].
//
// Round-6: zero-LDS wave-autonomous streaming (r5 structure) with the load
// pipeline actually kept in flight:
//  - template<EDGE>: interior bands (126/128) prefetch with a PURE
//    global_load_dwordx4 (no clamp/cndmask at issue) -> first use DEPTH rows
//    later -> compiler emits counted vmcnt, not per-row vmcnt(0) (r5's stall:
//    the zero-fixup cndmask consumed the just-issued load every row)
//  - DEPTH=6 rows in flight per wave (6 KB); 17 waves/CU -> ~100 KB/CU
//  - launch_bounds(256,4): grid-limited occupancy anyway; un-squeeze VGPRs

#define HIMG 4096
#define ODIM 1024
#define H2W  2048
#define NBAND 128            // bands of 8 output rows
#define WSEG 17              // waves per band row-span (62 unique out cols each)
#define WPI  (NBAND * WSEG)  // 2176 waves per image
#define NROWS 38             // x rows streamed per band
#define DEPTH 6              // load pipeline depth

template<bool EDGE>
__device__ __forceinline__ void run_band(
    const float* __restrict__ xb, float* __restrict__ out,
    const float (&w1)[9], const float (&w2)[9],
    int xr0, int o0, long ob, bool lE, bool rE, bool zs1, bool zs4, bool doSt)
{
    float4 buf[DEPTH];

    auto LD = [&](int t) -> float4 {
        const int gy = xr0 + t;
        if (EDGE) {
            int gyc = gy < 0 ? 0 : (gy > HIMG - 1 ? HIMG - 1 : gy);
            float4 v = *(const float4*)(xb + (long)gyc * HIMG);
            if (gy != gyc) { v.x = 0.f; v.y = 0.f; v.z = 0.f; v.w = 0.f; }
            return v;
        } else {
            return *(const float4*)(xb + (long)gy * HIMG);   // pure load
        }
    };

#pragma unroll
    for (int i = 0; i < DEPTH; ++i) buf[i] = LD(i);

    float accA[4] = {0,0,0,0}, accB[4] = {0,0,0,0};   // conv1 row rotation
    float dd0[4], dd1[4];
    float dA0 = 0, dA1 = 0, dB0 = 0, dB1 = 0, p0 = 0, p1 = 0;

    auto ROW = [&](int t, float (&dd)[4]) {
        float4 v = buf[t % DEPTH];
        if (t + DEPTH < NROWS) buf[t % DEPTH] = LD(t + DEPTH);
        float xl = __shfl_up(v.w, 1);
        float xr = __shfl_down(v.x, 1);
        if (lE) xl = 0.f;
        if (rE) xr = 0.f;
        const float xv[6] = {xl, v.x, v.y, v.z, v.w, xr};
#pragma unroll
        for (int j = 0; j < 4; ++j) {
            float d = accA[j];                     // completes conv row gy-1
            d = fmaf(w1[6], xv[j], d); d = fmaf(w1[7], xv[j+1], d); d = fmaf(w1[8], xv[j+2], d);
            float a = accB[j];                     // conv row gy
            a = fmaf(w1[3], xv[j], a); a = fmaf(w1[4], xv[j+1], a); a = fmaf(w1[5], xv[j+2], a);
            float b = w1[0] * xv[j];               // conv row gy+1
            b = fmaf(w1[1], xv[j+1], b); b = fmaf(w1[2], xv[j+2], b);
            dd[j] = d; accA[j] = a; accB[j] = b;
        }
    };

    ROW(0, dd0); ROW(1, dd0);                      // prime (discard)

#pragma unroll
    for (int s = 0; s < 18; ++s) {                 // 18 h2 rows: P = 2*o0-1+s
        ROW(2 * s + 2, dd0);
        ROW(2 * s + 3, dd1);
        float hvx = fmaxf(fmaxf(dd0[0], dd0[1]), fmaxf(dd1[0], dd1[1]));
        float hvy = fmaxf(fmaxf(dd0[2], dd0[3]), fmaxf(dd1[2], dd1[3]));
        if (EDGE) {                                // conv2 zero-pad rows
            const int P = 2 * o0 - 1 + s;
            if ((unsigned)P >= (unsigned)H2W) { hvx = 0.f; hvy = 0.f; }
        }
        const float su = __shfl_up(hvy, 1);        // h2[P][2oc-1]
        const float sd = __shfl_down(hvx, 1);      // h2[P][2oc+2]
        const float s1 = zs1 ? 0.f : su;
        const float s4 = zs4 ? 0.f : sd;
        float e0 = dA0;
        e0 = fmaf(w2[6], s1, e0); e0 = fmaf(w2[7], hvx, e0); e0 = fmaf(w2[8], hvy, e0);
        float a0 = dB0;
        a0 = fmaf(w2[3], s1, a0); a0 = fmaf(w2[4], hvx, a0); a0 = fmaf(w2[5], hvy, a0);
        float b0 = w2[0] * s1;  b0 = fmaf(w2[1], hvx, b0); b0 = fmaf(w2[2], hvy, b0);
        float e1 = dA1;
        e1 = fmaf(w2[6], hvx, e1); e1 = fmaf(w2[7], hvy, e1); e1 = fmaf(w2[8], s4, e1);
        float a1 = dB1;
        a1 = fmaf(w2[3], hvx, a1); a1 = fmaf(w2[4], hvy, a1); a1 = fmaf(w2[5], s4, a1);
        float b1 = w2[0] * hvx; b1 = fmaf(w2[1], hvy, b1); b1 = fmaf(w2[2], s4, b1);
        dA0 = a0; dB0 = b0; dA1 = a1; dB1 = b1;
        if (s >= 2) {
            if (s & 1) {                           // completed h3 row pair -> out
                const float res = fmaxf(fmaxf(p0, p1), fmaxf(e0, e1));
                if (doSt) out[ob + (long)((s - 3) >> 1) * ODIM] = res;
            } else {                               // stash h3 row 2a
                p0 = e0; p1 = e1;
            }
        }
    }
}

__global__ __launch_bounds__(256, 4)
void fused_v6(const float* __restrict__ x, const float* __restrict__ W1,
              const float* __restrict__ W2, float* __restrict__ out)
{
    const int lane = threadIdx.x & 63;
    const int gwid = blockIdx.x * 4 + (threadIdx.x >> 6);
    const int img  = (gwid >= WPI) ? 1 : 0;
    const int r    = gwid - img * WPI;
    const int band = r / WSEG;
    const int wseg = r - band * WSEG;

    float w1[9], w2[9];
#pragma unroll
    for (int i = 0; i < 9; ++i) { w1[i] = W1[i]; w2[i] = W2[i]; }

    // lane geometry: lanes 0/63 are sacrificial halo producers
    const int oc = 62 * wseg - 1 + lane;
    const int o0 = band * 8;
    int x0 = oc * 4;
    x0 = x0 < 0 ? 0 : (x0 > HIMG - 4 ? HIMG - 4 : x0);
    const bool lE   = (x0 == 0);
    const bool rE   = (x0 == HIMG - 4);
    const bool zs1  = (oc == 0);
    const bool zs4  = (oc == ODIM - 1);
    const bool doSt = (lane >= 1) & (lane <= 62) & ((unsigned)oc < (unsigned)ODIM);

    const int xr0 = 32 * band - 3;
    const float* xb = x + (long)img * HIMG * HIMG + x0;
    const long  ob  = (long)img * ODIM * ODIM + (long)o0 * ODIM + oc;

    if (band == 0 || band == NBAND - 1)
        run_band<true >(xb, out, w1, w2, xr0, o0, ob, lE, rE, zs1, zs4, doSt);
    else
        run_band<false>(xb, out, w1, w2, xr0, o0, ob, lE, rE, zs1, zs4, doSt);
}

extern "C" void kernel_launch(void* const* d_in, const int* in_sizes, int n_in,
                              void* d_out, int out_size, void* d_ws, size_t ws_size,
                              hipStream_t stream) {
    const float* x  = (const float*)d_in[0];
    const float* W1 = (const float*)d_in[1];
    const float* W2 = (const float*)d_in[2];
    float* out = (float*)d_out;

    // 2 images * 2176 waves = 4352 waves = 1088 blocks of 4 waves
    fused_v6<<<dim3(1088), dim3(256), 0, stream>>>(x, W1, W2, out);
}